// Round 6
// baseline (468.575 us; speedup 1.0000x reference)
//
#include <hip/hip_runtime.h>
#include <stdint.h>

#define QLEN 1024
#define KLEN 2048
#define BSZ  4
#define NH   16
#define HD   64
#define EMB  1024
#define PREVL 1024
#define SLOG2E 0.045084220027780106f   // (1/32) * log2(e): fold softmax scale + exp2 conversion

typedef __attribute__((ext_vector_type(4))) float f32x4;
typedef __attribute__((ext_vector_type(8))) short bf16x8;
typedef __attribute__((ext_vector_type(4))) short bf16x4;

__device__ __forceinline__ unsigned short f2bf(float f){
  unsigned u = __float_as_uint(f);
  u += 0x7fffu + ((u >> 16) & 1u);
  return (unsigned short)(u >> 16);
}

__device__ __forceinline__ void gload_lds16(const void* g, void* l){
  __builtin_amdgcn_global_load_lds((const __attribute__((address_space(1))) void*)g,
                                   (__attribute__((address_space(3))) void*)l, 16, 0, 0);
}

// ---------------- fused 5x W transpose: f32 [k][n] -> bf16 [n][k] ----------------
__global__ void txl_transpose5(const float* __restrict__ w0, const float* __restrict__ w1,
                               const float* __restrict__ w2, const float* __restrict__ w3,
                               const float* __restrict__ w4,
                               unsigned short* __restrict__ o0, unsigned short* __restrict__ o1,
                               unsigned short* __restrict__ o2, unsigned short* __restrict__ o3,
                               unsigned short* __restrict__ o4){
  const float* in; unsigned short* out;
  switch (blockIdx.z){
    case 0: in = w0; out = o0; break;
    case 1: in = w1; out = o1; break;
    case 2: in = w2; out = o2; break;
    case 3: in = w3; out = o3; break;
    default: in = w4; out = o4; break;
  }
  __shared__ float tile[32][33];
  int tx = threadIdx.x, ty = threadIdx.y;
  int k0 = blockIdx.y * 32, n0 = blockIdx.x * 32;
  #pragma unroll
  for (int j = 0; j < 32; j += 8)
    tile[ty + j][tx] = in[(size_t)(k0 + ty + j) * EMB + n0 + tx];
  __syncthreads();
  #pragma unroll
  for (int j = 0; j < 32; j += 8)
    out[(size_t)(n0 + ty + j) * EMB + k0 + tx] = f2bf(tile[tx][ty + j]);
}

// ---------------- GEMM: C[M][1024] = A[M][1024] @ Wt^T (+bias) ----------------
// Wt is bf16 [n][k]. A is f32 (MODE 0-3) or bf16 (MODE 4).
// MODE: 0=Q (writes Qu AND Qv, scaled), 1=K, 2=V(transposed), 3=R, 4=O(f32 out)
template<int MODE>
__global__ __launch_bounds__(256)
void txl_gemm(const void* __restrict__ Ag, const unsigned short* __restrict__ Wt,
              const float* __restrict__ bias, const float* __restrict__ Ub,
              const float* __restrict__ Vb, void* __restrict__ out0,
              void* __restrict__ out1){
  const int tid = threadIdx.x;
  const int lane = tid & 63, wave = tid >> 6;
  const int lr = lane & 15, lg = lane >> 4;
  const int wm = wave >> 1, wn = wave & 1;
  const int m0 = blockIdx.y * 128, n0 = blockIdx.x * 128;
  __shared__ unsigned short At[128 * 64];
  __shared__ unsigned short Bt[128 * 64];
  f32x4 acc[4][4] = {};

  for (int kt = 0; kt < EMB / 64; ++kt){
    const int k0 = kt * 64;
    __syncthreads();
    // ---- stage A tile [128][64] ----
    if constexpr (MODE == 4){
      const unsigned short* A = (const unsigned short*)Ag;
      #pragma unroll
      for (int j = 0; j < 4; ++j){
        int row = j * 32 + (tid >> 3);
        int g = (tid & 7) ^ (row & 7);
        gload_lds16(A + (size_t)(m0 + row) * EMB + k0 + g * 8, &At[j * 2048 + wave * 512]);
      }
    } else {
      const float* A = (const float*)Ag;
      int row = tid >> 1, hf = tid & 1;
      const f32x4* s4 = (const f32x4*)(A + (size_t)(m0 + row) * EMB + k0 + hf * 32);
      #pragma unroll
      for (int c = 0; c < 4; ++c){
        f32x4 a = s4[c * 2], b = s4[c * 2 + 1];
        bf16x8 pk;
        #pragma unroll
        for (int u = 0; u < 4; ++u){ pk[u] = (short)f2bf(a[u]); pk[u + 4] = (short)f2bf(b[u]); }
        int g = hf * 4 + c;
        *(bf16x8*)&At[row * 64 + (g ^ (row & 7)) * 8] = pk;
      }
    }
    // ---- stage B tile [128][64] ----
    #pragma unroll
    for (int j = 0; j < 4; ++j){
      int row = j * 32 + (tid >> 3);
      int g = (tid & 7) ^ (row & 7);
      gload_lds16(Wt + (size_t)(n0 + row) * EMB + k0 + g * 8, &Bt[j * 2048 + wave * 512]);
    }
    __syncthreads();
    #pragma unroll
    for (int ks = 0; ks < 2; ++ks){
      bf16x8 af[4], bfr[4];
      #pragma unroll
      for (int mb = 0; mb < 4; ++mb){
        int row = wm * 64 + mb * 16 + lr;
        af[mb] = *(const bf16x8*)&At[row * 64 + ((lg + 4 * ks) ^ (row & 7)) * 8];
      }
      #pragma unroll
      for (int nb = 0; nb < 4; ++nb){
        int row = wn * 64 + nb * 16 + lr;
        bfr[nb] = *(const bf16x8*)&Bt[row * 64 + ((lg + 4 * ks) ^ (row & 7)) * 8];
      }
      __builtin_amdgcn_s_setprio(1);
      #pragma unroll
      for (int mb = 0; mb < 4; ++mb)
        #pragma unroll
        for (int nb = 0; nb < 4; ++nb)
          acc[mb][nb] = __builtin_amdgcn_mfma_f32_16x16x32_bf16(af[mb], bfr[nb], acc[mb][nb], 0, 0, 0);
      __builtin_amdgcn_s_setprio(0);
    }
  }
  #pragma unroll
  for (int mb = 0; mb < 4; ++mb){
    #pragma unroll
    for (int nb = 0; nb < 4; ++nb){
      #pragma unroll
      for (int i = 0; i < 4; ++i){
        int m = m0 + wm * 64 + mb * 16 + 4 * lg + i;
        int n = n0 + wn * 64 + nb * 16 + lr;
        float v = acc[mb][nb][i];
        if constexpr (MODE == 0){
          int q = m >> 2, b = m & 3, h = n >> 6, d = n & 63;
          size_t idx = ((((size_t)b * NH + h) * QLEN) + q) * HD + d;
          ((unsigned short*)out0)[idx] = f2bf((v + bias[n] + Ub[n]) * SLOG2E);
          ((unsigned short*)out1)[idx] = f2bf((v + bias[n] + Vb[n]) * SLOG2E);
        } else if constexpr (MODE == 1){
          int kp = m >> 2, b = m & 3, h = n >> 6, d = n & 63;
          ((unsigned short*)out0)[((((size_t)b * NH + h) * KLEN) + kp) * HD + d] = f2bf(v + bias[n]);
        } else if constexpr (MODE == 2){
          int kp = m >> 2, b = m & 3, h = n >> 6, d = n & 63;
          ((unsigned short*)out0)[((((size_t)b * NH + h) * HD) + d) * KLEN + kp] = f2bf(v + bias[n]);
        } else if constexpr (MODE == 3){
          int h = n >> 6, d = n & 63;
          ((unsigned short*)out0)[((size_t)h * KLEN + m) * HD + d] = f2bf(v);
        } else {
          ((float*)out0)[(size_t)m * EMB + n] = v + bias[n];
        }
      }
    }
  }
}

// ---------------- fused attention: pipelined single-barrier k-loop ----------------
// 1024 blocks (XCD-swizzled): (b,h) x qt(8) x half(2). 4 waves x 32 q-rows.
// R in a 256-row LDS ring (64 new rows prefetched/tile); K/V reg-staged prefetch.
// Fixed-max exp2 softmax => partials linear; chunks combine via atomicAdd.
__global__ __launch_bounds__(256)
void txl_attn(const unsigned short* __restrict__ Qu, const unsigned short* __restrict__ Qv,
              const unsigned short* __restrict__ Kb, const unsigned short* __restrict__ Vt,
              const unsigned short* __restrict__ Rb, float* __restrict__ Opart,
              float* __restrict__ lspart){
  const int tid = threadIdx.x, lane = tid & 63, wave = tid >> 6;
  const int lr = lane & 15, lg = lane >> 4;
  // XCD swizzle: 128 consecutive work-items (8 hb's) per XCD
  const int wg = (blockIdx.x & 7) * 128 + (blockIdx.x >> 3);
  const int hb = wg >> 4;
  const int qt = (wg >> 1) & 7, half = wg & 1;
  const int h = hb & 15, b = hb >> 4;
  const int q0 = qt * 128;

  __shared__ unsigned short sm_p[4][32 * 64];   // 16 KB
  __shared__ unsigned short sm_k[64 * 64];      // 8 KB
  __shared__ unsigned short sm_v[64 * 64];      // 8 KB
  __shared__ unsigned short sm_r[256 * 64];     // 32 KB ring

  const unsigned short* quB = Qu + (((size_t)b * NH + h) * QLEN) * HD;
  const unsigned short* qvB = Qv + (((size_t)b * NH + h) * QLEN) * HD;
  const unsigned short* kB  = Kb + (((size_t)b * NH + h) * KLEN) * HD;
  const unsigned short* vB  = Vt + (((size_t)b * NH + h) * HD) * KLEN;
  const unsigned short* rB  = Rb + ((size_t)h * KLEN) * HD;

  const int nk0 = 2 * qt + 18;
  const int nk = nk0 < 32 ? nk0 : 32;
  const int kmid = nk >> 1;
  const int kc0 = half ? kmid : 0;
  const int kc1 = half ? nk : kmid;
  const int bb0 = 6 - 2 * wave;

  // ---- prologue: Q fragments direct global->reg ----
  bf16x8 qfu[2][2], qfv[2][2];
  #pragma unroll
  for (int j = 0; j < 2; ++j){
    int qrow = q0 + 32 * wave + 16 * j + lr;
    #pragma unroll
    for (int ks = 0; ks < 2; ++ks){
      qfu[j][ks] = *(const bf16x8*)(quB + (size_t)qrow * HD + (lg + 4 * ks) * 8);
      qfv[j][ks] = *(const bf16x8*)(qvB + (size_t)qrow * HD + (lg + 4 * ks) * 8);
    }
  }
  // ---- prologue: stage K/V(kc0) + R band [rb00, rb00+192) ----
  const int k00 = kc0 * 64;
  const int rb00 = k00 + 896 - q0;             // multiple of 64, >= 0
  {
    #pragma unroll
    for (int j = 0; j < 2; ++j){
      int row = j * 32 + (tid >> 3);
      int g = (tid & 7) ^ (row & 7);
      gload_lds16(kB + (size_t)(k00 + row) * HD + g * 8, &sm_k[j * 2048 + wave * 512]);
      gload_lds16(vB + (size_t)row * KLEN + k00 + g * 8, &sm_v[j * 2048 + wave * 512]);
    }
    #pragma unroll
    for (int jj = 0; jj < 6; ++jj){
      int row = jj * 32 + (tid >> 3);
      int r = rb00 + row;
      int rc = r < KLEN - 1 ? r : KLEN - 1;
      int g = (tid & 7) ^ (row & 7);
      int base = ((rb00 + jj * 32) & 255) * 64 + wave * 512;
      gload_lds16(rB + (size_t)rc * HD + g * 8, &sm_r[base]);
    }
  }
  __syncthreads();

  f32x4 o[2][4] = {};
  float ls[2][4] = {{0.f,0.f,0.f,0.f},{0.f,0.f,0.f,0.f}};

  for (int kt = kc0; kt < kc1; ++kt){
    const int k0 = kt * 64;
    const int rb0 = k0 + 896 - q0;
    const int s0 = rb0 & 255;                  // ring base slot for live band
    const bool more = (kt + 1 < kc1);

    // ---- issue next-tile stages FIRST (hidden under this tile's compute) ----
    f32x4 kreg[2], vreg[2];
    if (more){
      const int rs = rb0 + 192;                // 64 new ring rows
      #pragma unroll
      for (int jj = 0; jj < 2; ++jj){
        int row = jj * 32 + (tid >> 3);
        int r = rs + row;
        int rc = r < KLEN - 1 ? r : KLEN - 1;
        int g = (tid & 7) ^ (r & 7);
        int base = ((rs + jj * 32) & 255) * 64 + wave * 512;
        gload_lds16(rB + (size_t)rc * HD + g * 8, &sm_r[base]);
      }
      int srow = tid >> 3, scol = tid & 7;
      #pragma unroll
      for (int j = 0; j < 2; ++j){
        int row = j * 32 + srow;
        kreg[j] = *(const f32x4*)(kB + (size_t)(k0 + 64 + row) * HD + scol * 8);
        vreg[j] = *(const f32x4*)(vB + (size_t)row * KLEN + (k0 + 64) + scol * 8);
      }
    }

    // ---- content + position-band MFMAs ----
    f32x4 sc[2][4] = {};
    f32x4 tq[2][5] = {};
    __builtin_amdgcn_s_setprio(1);
    #pragma unroll
    for (int ks = 0; ks < 2; ++ks){
      #pragma unroll
      for (int nb = 0; nb < 4; ++nb){
        int row = nb * 16 + lr;
        bf16x8 bb = *(const bf16x8*)&sm_k[row * 64 + ((lg + 4 * ks) ^ (row & 7)) * 8];
        sc[0][nb] = __builtin_amdgcn_mfma_f32_16x16x32_bf16(qfu[0][ks], bb, sc[0][nb], 0, 0, 0);
        sc[1][nb] = __builtin_amdgcn_mfma_f32_16x16x32_bf16(qfu[1][ks], bb, sc[1][nb], 0, 0, 0);
      }
      #pragma unroll
      for (int x6 = 0; x6 < 6; ++x6){
        int slot = (s0 + (bb0 + x6) * 16 + lr) & 255;
        bf16x8 br = *(const bf16x8*)&sm_r[slot * 64 + ((lg + 4 * ks) ^ (slot & 7)) * 8];
        if (x6 < 5) tq[1][x6]     = __builtin_amdgcn_mfma_f32_16x16x32_bf16(qfv[1][ks], br, tq[1][x6], 0, 0, 0);
        if (x6 > 0) tq[0][x6 - 1] = __builtin_amdgcn_mfma_f32_16x16x32_bf16(qfv[0][ks], br, tq[0][x6 - 1], 0, 0, 0);
      }
    }
    __builtin_amdgcn_s_setprio(0);

    // ---- diagonal select + mask + exp2 (fixed-max), deferred row-sum, write P ----
    #pragma unroll
    for (int j = 0; j < 2; ++j){
      const int qbase = q0 + 32 * wave + 16 * j;
      const bool mk = (k0 + 63 > qbase + PREVL);
      #pragma unroll
      for (int i = 0; i < 4; ++i){
        int qq = 4 * lg + i;
        int t = lr + 15 - qq;
        int srcl = (lane & 48) | (t & 15);
        int hi = t >> 4;
        float wv[5];
        #pragma unroll
        for (int x = 0; x < 5; ++x) wv[x] = __shfl(tq[j][x][i], srcl, 64);
        float rs = 0.f;
        #pragma unroll
        for (int nb = 0; nb < 4; ++nb){
          float s = sc[j][nb][i] + (hi ? wv[nb + 1] : wv[nb]);
          if (mk && (k0 + nb * 16 + lr > qbase + qq + PREVL)) s = -1e30f;
          float p = exp2f(s);
          rs += p;
          int kk = nb * 16 + lr, prow = 16 * j + qq;
          sm_p[wave][prow * 64 + (((kk >> 3) ^ (prow & 7)) << 3) + (kk & 7)] = f2bf(p);
        }
        ls[j][i] += rs;
      }
    }
    asm volatile("s_waitcnt lgkmcnt(0)" ::: "memory");

    // ---- PV ----
    __builtin_amdgcn_s_setprio(1);
    #pragma unroll
    for (int ks = 0; ks < 2; ++ks){
      bf16x8 pa[2];
      #pragma unroll
      for (int j = 0; j < 2; ++j){
        int row = 16 * j + lr;
        pa[j] = *(const bf16x8*)&sm_p[wave][row * 64 + ((lg + 4 * ks) ^ (row & 7)) * 8];
      }
      #pragma unroll
      for (int db = 0; db < 4; ++db){
        int row = db * 16 + lr;
        bf16x8 bv = *(const bf16x8*)&sm_v[row * 64 + ((lg + 4 * ks) ^ (row & 7)) * 8];
        o[0][db] = __builtin_amdgcn_mfma_f32_16x16x32_bf16(pa[0], bv, o[0][db], 0, 0, 0);
        o[1][db] = __builtin_amdgcn_mfma_f32_16x16x32_bf16(pa[1], bv, o[1][db], 0, 0, 0);
      }
    }
    __builtin_amdgcn_s_setprio(0);

    __syncthreads();           // drains vmcnt: R(t+1) landed, kreg/vreg arrived
    if (more){
      int srow = tid >> 3, scol = tid & 7;
      #pragma unroll
      for (int j = 0; j < 2; ++j){
        int row = j * 32 + srow;
        int cl = scol ^ (row & 7);
        *(f32x4*)&sm_k[row * 64 + cl * 8] = kreg[j];
        *(f32x4*)&sm_v[row * 64 + cl * 8] = vreg[j];
      }
      __syncthreads();         // K/V(t+1) visible
    }
  }

  // ---- partial accumulation (exactly 2 commutative f32 adds per element) ----
  const int slot = hb * 8 + qt;
  float* Ob = Opart + (size_t)slot * 8192;
  #pragma unroll
  for (int j = 0; j < 2; ++j){
    #pragma unroll
    for (int i = 0; i < 4; ++i){
      float s = ls[j][i];
      s += __shfl_xor(s, 1); s += __shfl_xor(s, 2);
      s += __shfl_xor(s, 4); s += __shfl_xor(s, 8);
      int q = 32 * wave + 16 * j + 4 * lg + i;
      if (lr == 0) atomicAdd(&lspart[slot * 128 + q], s);
      #pragma unroll
      for (int db = 0; db < 4; ++db)
        atomicAdd(&Ob[q * 64 + db * 16 + lr], o[j][db][i]);
    }
  }
}

// ---------------- normalize summed partials -> alpha bf16 ----------------
__global__ __launch_bounds__(256)
void txl_reduce(const float* __restrict__ Opart, const float* __restrict__ lspart,
                unsigned short* __restrict__ alpha){
  const int rb = blockIdx.x;                   // 512 = hb*8 + qt
  const int qt = rb & 7, hb = rb >> 3;
  const int h = hb & 15, b = hb >> 4;
  const f32x4* O = (const f32x4*)(Opart + (size_t)rb * 8192);
  const float* l = lspart + rb * 128;
  const int q0 = qt * 128;
  #pragma unroll
  for (int u = 0; u < 8; ++u){
    int e4 = u * 256 + threadIdx.x;
    int q = e4 >> 4, d0 = (e4 & 15) * 4;
    f32x4 ov = O[e4];
    float inv = 1.0f / l[q];
    bf16x4 r;
    #pragma unroll
    for (int e = 0; e < 4; ++e) r[e] = (short)f2bf(ov[e] * inv);
    *(bf16x4*)(alpha + ((size_t)(q0 + q) * BSZ + b) * EMB + (h << 6) + d0) = r;
  }
}

extern "C" void kernel_launch(void* const* d_in, const int* in_sizes, int n_in,
                              void* d_out, int out_size, void* d_ws, size_t ws_size,
                              hipStream_t stream) {
  const float* query = (const float*)d_in[0];
  const float* key   = (const float*)d_in[1];
  const float* value = (const float*)d_in[2];
  const float* pos   = (const float*)d_in[3];
  const float* U     = (const float*)d_in[4];
  const float* V     = (const float*)d_in[5];
  const float* Wq    = (const float*)d_in[6];
  const float* bq    = (const float*)d_in[7];
  const float* Wk    = (const float*)d_in[8];
  const float* bk    = (const float*)d_in[9];
  const float* Wv    = (const float*)d_in[10];
  const float* bv    = (const float*)d_in[11];
  const float* Wp    = (const float*)d_in[12];
  const float* Wo    = (const float*)d_in[13];
  const float* bo    = (const float*)d_in[14];

  char* w = (char*)d_ws;
  const size_t MB = 1u << 20;
  unsigned short* WqT = (unsigned short*)(w + 0 * MB);
  unsigned short* WkT = (unsigned short*)(w + 2 * MB);
  unsigned short* WvT = (unsigned short*)(w + 4 * MB);
  unsigned short* WpT = (unsigned short*)(w + 6 * MB);
  unsigned short* WoT = (unsigned short*)(w + 8 * MB);
  unsigned short* Qu  = (unsigned short*)(w + 10 * MB);
  unsigned short* Qv  = (unsigned short*)(w + 18 * MB);
  unsigned short* Kb  = (unsigned short*)(w + 26 * MB);
  unsigned short* Vt  = (unsigned short*)(w + 42 * MB);
  unsigned short* Rb  = (unsigned short*)(w + 58 * MB);
  float*          Opart  = (float*)(w + 62 * MB);        // 16 MB, memset 0
  float*          lspart = (float*)(w + 78 * MB);        // 256 KB, memset 0
  unsigned short* alpha  = (unsigned short*)(w + 79 * MB);

  hipMemsetAsync(w + 62 * MB, 0, 16 * MB + 256 * 1024, stream);

  txl_transpose5<<<dim3(32, 32, 5), dim3(32, 8), 0, stream>>>(Wq, Wk, Wv, Wp, Wo,
                                                              WqT, WkT, WvT, WpT, WoT);

  txl_gemm<3><<<dim3(8, 16), 256, 0, stream>>>((const void*)pos,   WpT, nullptr, nullptr, nullptr, (void*)Rb, nullptr);
  txl_gemm<0><<<dim3(8, 32), 256, 0, stream>>>((const void*)query, WqT, bq, U, V, (void*)Qu, (void*)Qv);
  txl_gemm<1><<<dim3(8, 64), 256, 0, stream>>>((const void*)key,   WkT, bk, nullptr, nullptr, (void*)Kb, nullptr);
  txl_gemm<2><<<dim3(8, 64), 256, 0, stream>>>((const void*)value, WvT, bv, nullptr, nullptr, (void*)Vt, nullptr);

  txl_attn<<<dim3(1024), 256, 0, stream>>>(Qu, Qv, Kb, Vt, Rb, Opart, lspart);
  txl_reduce<<<dim3(512), 256, 0, stream>>>(Opart, lspart, alpha);

  txl_gemm<4><<<dim3(8, 32), 256, 0, stream>>>((const void*)alpha, WoT, bo, nullptr, nullptr, d_out, nullptr);
}